// Round 4
// baseline (266.099 us; speedup 1.0000x reference)
//
#include <hip/hip_runtime.h>
#include <stdint.h>

#define NR 32768
#define MM 8
#define NCLS 100
#define HALFN 1048576u
#define HROW 128  // fp16 per h-plane row (256 B, power of 2) + XOR swizzle
#define PSS 12    // float stride for per-row partial arrays

#define LOG2E 1.4426950408889634f
#define LN2F  0.6931471805599453f

typedef _Float16 h8 __attribute__((ext_vector_type(8)));
typedef _Float16 h4 __attribute__((ext_vector_type(4)));
typedef float f4 __attribute__((ext_vector_type(4)));
typedef unsigned long long ull;

// ---------------- threefry2x32 (exact JAX semantics) ----------------
__host__ __device__ inline void tf2x32(uint32_t k0, uint32_t k1, uint32_t x0, uint32_t x1,
                                       uint32_t& o0, uint32_t& o1) {
  uint32_t ks0 = k0, ks1 = k1, ks2 = k0 ^ k1 ^ 0x1BD11BDAu;
  x0 += ks0; x1 += ks1;
#define TFR(r) { x0 += x1; x1 = (x1 << r) | (x1 >> (32 - r)); x1 ^= x0; }
  TFR(13) TFR(15) TFR(26) TFR(6)  x0 += ks1; x1 += ks2 + 1u;
  TFR(17) TFR(29) TFR(16) TFR(24) x0 += ks2; x1 += ks0 + 2u;
  TFR(13) TFR(15) TFR(26) TFR(6)  x0 += ks0; x1 += ks1 + 3u;
  TFR(17) TFR(29) TFR(16) TFR(24) x0 += ks1; x1 += ks2 + 4u;
  TFR(13) TFR(15) TFR(26) TFR(6)  x0 += ks2; x1 += ks0 + 5u;
#undef TFR
  o0 = x0; o1 = x1;
}

// template dtype auto-detect: float32 {0,1.0f} / int32 {0,1} / bytes. 4 ones expected.
__device__ inline int load_tmpl(const void* p, int lane) {
  const unsigned* pi = (const unsigned*)p;
  unsigned w = pi[lane];
  ull okF = __ballot(w == 0u || w == 0x3F800000u);
  ull onF = __ballot(w == 0x3F800000u);
  ull okI = __ballot(w <= 1u);
  ull onI = __ballot(w == 1u);
  if (okF == ~0ull && __popcll(onF) == 4) return (w == 0x3F800000u) ? 1 : 0;
  if (okI == ~0ull && __popcll(onI) == 4) return (int)w;
  const unsigned char* pb = (const unsigned char*)p;
  return pb[lane] ? 1 : 0;
}

__device__ inline uint32_t packh2(float a, float b) {
  union { _Float16 h[2]; uint32_t u; } cv;
  cv.h[0] = (_Float16)a; cv.h[1] = (_Float16)b;
  return cv.u;
}

// flip mask from template ballot: for each of the 4 template-one positions p,
// set bit rank(p) where rank = #{keys < key_p}. Keys are unique (lane in low bits),
// so this equals the stable-argsort rank; identical to the old O(64^2) path.
__device__ inline ull flip_mask(ull tmask, uint32_t key) {
  ull fm = 0;
  while (tmask) {
    int p = __ffsll((long long)tmask) - 1;
    tmask &= tmask - 1;
    uint32_t kp = (uint32_t)__builtin_amdgcn_readlane((int)key, p);
    fm |= 1ull << __popcll(__ballot(key < kp));
  }
  return fm;
}

// ---------------- stage1p: per-row transform + weight prep fused ----------------
// blocks 0..2047: 16 rows/block, 4 rows/wave {b*8+wv*2, +1, +16384, +16385}.
// Each wave computes BOTH threefry keys for its own row-pairs and consumes both
// outputs of each tf2x32 in-register -> no LDS exchange, no barrier.
// blocks 2048..2303: W2 frag pack; 2304..2335: W1+B1 frag pack (x log2e, bias on
// K-slot 8); 2336..2360: cb64; 2361: B2s = B2 * log2e.
__global__ __launch_bounds__(256) void stage1p(
    const float* __restrict__ x, const int* __restrict__ y, const int* __restrict__ perm,
    const void* tmap, const void* traw,
    uint32_t km0, uint32_t km1, uint32_t kr0, uint32_t kr1,
    const float* __restrict__ W2, const float* __restrict__ W1,
    const float* __restrict__ B1, const float* __restrict__ B2,
    const float* __restrict__ centroids,
    _Float16* __restrict__ Wp, _Float16* __restrict__ Wp1, float* __restrict__ B2s,
    ull* __restrict__ cb64,
    uint32_t* __restrict__ xp16, uint32_t* __restrict__ xm16,
    ull* __restrict__ targ, ull* __restrict__ xb,
    float* __restrict__ winv, unsigned char* __restrict__ poslist, int* __restrict__ nposA) {
  int b = blockIdx.x, tid = threadIdx.x;
  if (b >= 2048) {
    int pb = b - 2048;
    if (pb < 256) {
      // W2: gid = ((m*8+kt)*16+NT)*64 + q*16+lr ; elem j = W2[m][kt*32+q*8+j][NT*16+lr]
      int gid = pb * 256 + tid;
      int lane6 = gid & 63, frag = gid >> 6;
      int NT = frag & 15, kt = (frag >> 4) & 7, m = frag >> 7;
      int q = lane6 >> 4, lr = lane6 & 15;
      const float* src = W2 + (size_t)m * 65536 + (size_t)(kt * 32 + q * 8) * 256 + NT * 16 + lr;
      h8 v;
#pragma unroll
      for (int j = 0; j < 8; j++) v[j] = (_Float16)src[j * 256];
      *(h8*)(Wp + (size_t)gid * 8) = v;
    } else if (pb < 288) {
      // W1 frag (m, t), scaled by log2e: lane(q,lr) j -> A[hid=t*16+lr][k=q*8+j]:
      // q0 = W1[j][hid]*log2e; (q1,j0) = B1[hid]*log2e (bias rides K-slot 8); else 0
      int idx = (pb - 256) * 256 + tid;  // 8192 total
      int lane = idx & 63, t = (idx >> 6) & 15, m = idx >> 10;
      int q = lane >> 4, lr = lane & 15;
      h8 v;
#pragma unroll
      for (int j = 0; j < 8; j++) {
        float val = 0.0f;
        if (q == 0) val = W1[(size_t)(m * 8 + j) * 256 + t * 16 + lr] * LOG2E;
        else if (q == 1 && j == 0) val = B1[m * 256 + t * 16 + lr] * LOG2E;
        v[j] = (_Float16)val;
      }
      *(h8*)(Wp1 + (size_t)idx * 8) = v;
    } else if (pb < 313) {
      // centroid bits: 4 classes per block, one wave each (25 blocks x 4 = 100)
      int c = (pb - 288) * 4 + (tid >> 6);
      int lane = tid & 63;
      ull bits = __ballot(centroids[c * 64 + perm[lane]] > 0.0f);
      if (lane == 0 && c < NCLS) cb64[c] = bits;
    } else {
      // B2s = B2 * log2e (2048 floats)
#pragma unroll
      for (int j = 0; j < 8; j++) B2s[tid * 8 + j] = B2[tid * 8 + j] * LOG2E;
    }
    return;
  }

  int wv = tid >> 6, lane = tid & 63;
  int tm = load_tmpl(tmap, lane);
  int tr = load_tmpl(traw, lane);
  ull tmm = __ballot(tm != 0);
  ull trm = __ballot(tr != 0);
  int pv = perm[lane];

  int nbase = b * 8 + wv * 2;  // < 16384
  uint32_t bmv[4], brv[4];
  {
    uint32_t iA = (uint32_t)(nbase * 64 + lane);
    uint32_t iB = iA + 64u;
    tf2x32(km0, km1, iA, iA + HALFN, bmv[0], bmv[2]);
    tf2x32(kr0, kr1, iA, iA + HALFN, brv[0], brv[2]);
    tf2x32(km0, km1, iB, iB + HALFN, bmv[1], bmv[3]);
    tf2x32(kr0, kr1, iB, iB + HALFN, brv[1], brv[3]);
  }
  const int nn[4] = {nbase, nbase + 1, nbase + 16384, nbase + 16385};
#pragma unroll
  for (int rr = 0; rr < 4; rr++) {
    int n = nn[rr];
    float xpv = x[(size_t)n * 64 + pv];
    // rank key: ((bits>>9)<<6)|lane == stable argsort key of the uniform (unique)
    uint32_t kmk = ((bmv[rr] >> 9) << 6) | (uint32_t)lane;
    uint32_t krk = ((brv[rr] >> 9) << 6) | (uint32_t)lane;
    ull fm = flip_mask(tmm, kmk);
    ull fr = flip_mask(trm, krk);
    float xmv = ((fm >> lane) & 1ull) ? -xpv : xpv;
    float rfv = ((fr >> lane) & 1ull) ? -xpv : xpv;
    // fp16 outputs (identical rounding to former in-kernel cvt)
    float xp_o = __shfl_xor(xpv, 1);
    float xm_o = __shfl_xor(xmv, 1);
    if ((lane & 1) == 0) {
      xp16[n * 32 + (lane >> 1)] = packh2(xpv, xp_o);
      xm16[n * 32 + (lane >> 1)] = packh2(xmv, xm_o);
    }
    ull t64 = __ballot(rfv > 0.0f);
    ull b64v = __ballot(xpv > 0.0f);

    int c1 = y[(size_t)n * NCLS + lane] > 0;
    int c2 = (lane < NCLS - 64) ? (y[(size_t)n * NCLS + 64 + lane] > 0) : 0;
    ull p0 = __ballot(c1);
    ull p1 = __ballot(c2);
    int cnt0 = __popcll(p0);
    float cnt = (float)(cnt0 + __popcll(p1));

    unsigned char* pl = poslist + (size_t)n * 64;
    ull below = (lane == 0) ? 0ull : (~0ull >> (64 - lane));
    if (c1) pl[__popcll(p0 & below)] = (unsigned char)lane;
    if (c2) pl[cnt0 + __popcll(p1 & below)] = (unsigned char)(64 + lane);

    if (lane == 0) {
      targ[n] = t64;
      xb[n] = b64v;
      winv[n] = 1.0f / cnt;
      nposA[n] = cnt0 + __popcll(p1);
    }
  }
}

// ---------------- fused MLP + loss epilogue + hamming slice ----
// grid (512, 8, 3); block 512 (8 waves). z0 = map, z1 = net, z2 = hamming.
// LDS layouts are power-of-2 stride + XOR swizzle (guide G4/T2, HW-verified):
//   h:  fp16, row*128 + (col ^ ((row&7)<<3))   -- 256 B rows, 16B-chunk XOR
//   lg: f32,  row*256 + (col ^ ((row&7)<<2))   -- 1 KB rows, 16B-chunk XOR
// Swapped mfma operands: acc reg-dim walks COLUMNS; bias preloaded into acc.
// Pass 0: no logit staging; lse/max from ps/pm partials; picked/hit extracted
// at the owner lane. Pass 1 stages logits (swizzled) for the poslist gather.
__global__ __launch_bounds__(512, 8) void mapnet8(
    const uint32_t* __restrict__ Xm16, const uint32_t* __restrict__ Xp16,
    const _Float16* __restrict__ Wp1, const _Float16* __restrict__ Wp,
    const float* __restrict__ B2s,
    const ull* __restrict__ targ, const float* __restrict__ winv,
    const unsigned char* __restrict__ poslist, const int* __restrict__ nposA,
    const ull* __restrict__ cb64, const ull* __restrict__ xb,
    float* __restrict__ accbuf) {
  __shared__ union {
    _Float16 h[64 * HROW];     // fp16 h-plane, 16384 B (swizzled)
    float lg[32 * 256];        // logit staging, 32768 B (swizzled)
  } u;
  __shared__ float ps[64 * PSS];   // per-row exp2-sum partials [row][wv]
  __shared__ float pm[64 * PSS];   // per-row max partials (pass 0)
  __shared__ float mvA[64];        // combined per-row max (pass 0)
  __shared__ int   tA[64];         // per-row target byte (pass 0)
  __shared__ float sl[3];          // block accumulators
  const int tid = threadIdx.x, lane = tid & 63, wv = tid >> 6;
  const int q = lane >> 4, lr = lane & 15;
  const int m = blockIdx.y, pass = blockIdx.z;
  const int n0 = blockIdx.x * 64;
  if (tid < 3) sl[tid] = 0.0f;

  if (pass == 2) {
    // hamming + cnt: 8 rows per block (one per wave)
    __syncthreads();
    int flat = blockIdx.y * 512 + blockIdx.x;   // 0..4095
    int n = flat * 8 + wv;
    ull xv = xb[n];
    float px = (float)__popcll(xv);
    int np = nposA[n];
    float hs = 0.0f;
    if (lane < np) {
      int c = poslist[(size_t)n * 64 + lane];
      ull cb = cb64[c];
      hs = px + (float)__popcll(cb) - 2.0f * (float)__popcll(xv & cb);
    }
#pragma unroll
    for (int off = 1; off < 64; off <<= 1) hs += __shfl_xor(hs, off);
    if (lane == 0) {
      atomicAdd(&sl[0], hs);
      atomicAdd(&sl[1], (float)np);
    }
    __syncthreads();
    if (tid == 0) {
      float* slot = accbuf + (flat & 127) * 8;
      atomicAdd(&slot[3], sl[0]);
      atomicAdd(&slot[4], sl[1]);
    }
    return;
  }

  const uint32_t* Xin = pass ? Xp16 : Xm16;

  // ---- L1 (transposed): wave wv covers rowblock rb = wv&3, t-range (wv>>2)*8..+7
  // W1/B1 pre-scaled by log2e; bias rides K-slot 8 (af[0]=1 on q==1 lanes).
  const int rb = wv & 3, tbase = (wv >> 2) * 8;
  const int hsw = (lr & 7) << 3;   // h-plane XOR key for this lane's rows
  h8 af;
  {
    const _Float16* xsrc = (const _Float16*)(Xin + (size_t)(n0 + rb * 16 + lr) * 32) + m * 8;
    h8 xv = *(const h8*)xsrc;
    h8 zero = {(_Float16)0.0f, (_Float16)0.0f, (_Float16)0.0f, (_Float16)0.0f,
               (_Float16)0.0f, (_Float16)0.0f, (_Float16)0.0f, (_Float16)0.0f};
    af = (q == 0) ? xv : zero;
    if (q == 1) af[0] = (_Float16)1.0f;
  }
#pragma unroll 4
  for (int tt = 0; tt < 8; tt++) {
    int t = tbase + tt;
    h8 wfrag = *(const h8*)(Wp1 + ((size_t)(m * 16 + t) * 64 + lane) * 8);
    f4 z = __builtin_amdgcn_mfma_f32_16x16x32_f16(wfrag, af, (f4){0.f, 0.f, 0.f, 0.f}, 0, 0, 0);
    h4 pk;
#pragma unroll
    for (int reg = 0; reg < 4; reg++) {
      float z2 = z[reg];  // (z+b1)*log2e
      // silu*log2e = z2 * rcp(1 + exp2(-z2)); neg is a free input modifier
      pk[reg] = (_Float16)(z2 * __builtin_amdgcn_rcpf(1.0f + __builtin_amdgcn_exp2f(-z2)));
    }
    *(h4*)(u.h + (size_t)(rb * 16 + lr) * HROW + ((t * 16 + q * 4) ^ hsw)) = pk;
  }
  __syncthreads();

  // ---- K loop (swapped operands): acc4[rt][nt][reg] =
  //      logit2[n = rt*16+lr][col = wv*32 + nt*16 + q*4 + reg], bias pre-loaded ----
  f4 acc4[4][2];
  {
    f4 bv0 = *(const f4*)(B2s + m * 256 + wv * 32 + q * 4);
    f4 bv1 = *(const f4*)(B2s + m * 256 + wv * 32 + 16 + q * 4);
#pragma unroll
    for (int rt = 0; rt < 4; rt++) { acc4[rt][0] = bv0; acc4[rt][1] = bv1; }
  }
  const size_t wbase = (size_t)m * 65536;
#pragma unroll 2
  for (int kt = 0; kt < 8; kt++) {
    h8 bh0 = *(const h8*)(Wp + wbase + (((size_t)kt * 16 + wv * 2 + 0) * 64 + lane) * 8);
    h8 bh1 = *(const h8*)(Wp + wbase + (((size_t)kt * 16 + wv * 2 + 1) * 64 + lane) * 8);
#pragma unroll
    for (int rt = 0; rt < 4; rt++) {
      // swizzled single ds_read_b128 A-frag
      h8 ah = *(const h8*)(u.h + (size_t)(rt * 16 + lr) * HROW + ((kt * 32 + q * 8) ^ hsw));
      acc4[rt][0] = __builtin_amdgcn_mfma_f32_16x16x32_f16(bh0, ah, acc4[rt][0], 0, 0, 0);
      acc4[rt][1] = __builtin_amdgcn_mfma_f32_16x16x32_f16(bh1, ah, acc4[rt][1], 0, 0, 0);
    }
  }

  // ---- in-register softmax partials: row rt*16+lr, this wave's 32 cols ----
  float rsum[4], rmax[4];
#pragma unroll
  for (int rt = 0; rt < 4; rt++) {
    f4 l0 = acc4[rt][0], l1 = acc4[rt][1];
    float s = 0.0f;
#pragma unroll
    for (int reg = 0; reg < 4; reg++)
      s += __builtin_amdgcn_exp2f(l0[reg]) + __builtin_amdgcn_exp2f(l1[reg]);
    rsum[rt] = s;
    if (pass == 0) {
      float mv = fmaxf(l0[0], l1[0]);
#pragma unroll
      for (int reg = 1; reg < 4; reg++) mv = fmaxf(mv, fmaxf(l0[reg], l1[reg]));
      rmax[rt] = mv;
    }
  }
#pragma unroll
  for (int rt = 0; rt < 4; rt++) {
    rsum[rt] += __shfl_xor(rsum[rt], 16);
    rsum[rt] += __shfl_xor(rsum[rt], 32);
  }
  if (pass == 0) {
#pragma unroll
    for (int rt = 0; rt < 4; rt++) {
      rmax[rt] = fmaxf(rmax[rt], __shfl_xor(rmax[rt], 16));
      rmax[rt] = fmaxf(rmax[rt], __shfl_xor(rmax[rt], 32));
    }
  }
  if (lane < 16) {
#pragma unroll
    for (int rt = 0; rt < 4; rt++) {
      ps[(rt * 16 + lane) * PSS + wv] = rsum[rt];
      if (pass == 0) pm[(rt * 16 + lane) * PSS + wv] = rmax[rt];
    }
  }

  if (pass == 0) {
    // ---- owner-lane extraction: no logit staging ----
    __syncthreads();
    float myLse = 0.0f;
    if (tid < 64) {
      int row = tid, n = n0 + row;
      f4 s0 = *(const f4*)(ps + row * PSS);
      f4 s1 = *(const f4*)(ps + row * PSS + 4);
      f4 ss = s0 + s1;
      float s = (ss[0] + ss[1]) + (ss[2] + ss[3]);
      f4 m0 = *(const f4*)(pm + row * PSS);
      f4 m1 = *(const f4*)(pm + row * PSS + 4);
      float mv = fmaxf(fmaxf(fmaxf(m0[0], m0[1]), fmaxf(m0[2], m0[3])),
                       fmaxf(fmaxf(m1[0], m1[1]), fmaxf(m1[2], m1[3])));
      mvA[row] = mv;
      tA[row] = (int)((targ[n] >> (m * 8)) & 0xFFull);
      myLse = __builtin_amdgcn_logf(s);   // base-2 lse (bias already in logits)
    }
    __syncthreads();
    float pick = 0.0f, hit = 0.0f;
    const int cbase = wv * 32 + q * 4;
#pragma unroll
    for (int rt = 0; rt < 4; rt++) {
      int row = rt * 16 + lr;
      int d0 = tA[row] - cbase;           // LDS broadcast read
#pragma unroll
      for (int nt = 0; nt < 2; nt++) {
        int d = d0 - nt * 16;
        if ((unsigned)d < 4u) {
          f4 f = acc4[rt][nt];
          float v = f[0];
          v = (d == 1) ? f[1] : v;
          v = (d == 2) ? f[2] : v;
          v = (d == 3) ? f[3] : v;
          pick += v;
          hit += (v == mvA[row]) ? 1.0f : 0.0f;
        }
      }
    }
    float lossC = myLse - pick;
#pragma unroll
    for (int off = 1; off < 64; off <<= 1) {
      lossC += __shfl_xor(lossC, off);
      hit += __shfl_xor(hit, off);
    }
    if (lane == 0) {
      atomicAdd(&sl[0], lossC);
      atomicAdd(&sl[2], hit);
    }
  } else {
    // ---- pass 1: stage logits (swizzled) for the poslist gather; two 32-row phases ----
    float partLoss = 0.0f;
    const int lsw = (lr & 7) << 2;   // lg XOR key for this lane's written rows
    for (int ph = 0; ph < 2; ph++) {
      __syncthreads();
#pragma unroll
      for (int rt2 = 0; rt2 < 2; rt2++) {
#pragma unroll
        for (int nt = 0; nt < 2; nt++)
          *(f4*)&u.lg[(rt2 * 16 + lr) * 256 + ((wv * 32 + nt * 16 + q * 4) ^ lsw)] =
              acc4[ph * 2 + rt2][nt];
      }
      __syncthreads();
      int rl = tid >> 4;                   // local row 0..31
      int grow = ph * 32 + rl;             // row within block
      int n = n0 + grow;
      int cl = tid & 15;
      const float* lrow = u.lg + rl * 256;
      const int rsw = (rl & 7) << 2;       // read-side XOR key
      int np = nposA[n];
      const unsigned char* pl = poslist + (size_t)n * 64;
      float sp = 0.0f;
      for (int j2 = cl; j2 < np; j2 += 16) {
        int c = pl[j2];
        int t = (int)((cb64[c] >> (m * 8)) & 0xFFull);
        sp += lrow[t ^ rsw];
      }
#pragma unroll
      for (int off = 1; off < 16; off <<= 1) sp += __shfl_xor(sp, off);
      if (cl == 0) {
        f4 s0 = *(const f4*)(ps + grow * PSS);
        f4 s1 = *(const f4*)(ps + grow * PSS + 4);
        f4 ss = s0 + s1;
        float s = (ss[0] + ss[1]) + (ss[2] + ss[3]);
        partLoss += __builtin_amdgcn_logf(s) - winv[n] * sp;
      }
    }
    partLoss += __shfl_xor(partLoss, 16);
    partLoss += __shfl_xor(partLoss, 32);
    if (lane == 0) atomicAdd(&sl[1], partLoss);
  }

  __syncthreads();
  if (tid == 0) {
    float* slot = accbuf + (blockIdx.x & 127) * 8;
    if (pass == 0) {
      atomicAdd(&slot[0], sl[0]);
      atomicAdd(&slot[2], sl[2]);
    } else {
      atomicAdd(&slot[1], sl[1]);
    }
  }
}

__global__ __launch_bounds__(128) void finalk(const float* __restrict__ accbuf, float* __restrict__ out) {
  int t = threadIdx.x;  // 0..127
  float v0 = accbuf[t * 8 + 0], v1 = accbuf[t * 8 + 1], v2 = accbuf[t * 8 + 2];
  float v3 = accbuf[t * 8 + 3], v4 = accbuf[t * 8 + 4];
#pragma unroll
  for (int off = 1; off < 64; off <<= 1) {
    v0 += __shfl_xor(v0, off); v1 += __shfl_xor(v1, off); v2 += __shfl_xor(v2, off);
    v3 += __shfl_xor(v3, off); v4 += __shfl_xor(v4, off);
  }
  __shared__ float s[2][5];
  if ((t & 63) == 0) {
    s[t >> 6][0] = v0; s[t >> 6][1] = v1; s[t >> 6][2] = v2; s[t >> 6][3] = v3; s[t >> 6][4] = v4;
  }
  __syncthreads();
  if (t == 0) {
    float a0 = s[0][0] + s[1][0], a1 = s[0][1] + s[1][1], a2 = s[0][2] + s[1][2];
    float a3 = s[0][3] + s[1][3], a4 = s[0][4] + s[1][4];
    // losses accumulated in base-2 (exp2-domain logits): scale back by ln2 here.
    float netLoss = a1 * LN2F / (float)NR;
    float mapLoss = a0 * LN2F / (float)NR;
    out[0] = netLoss + mapLoss;
    out[1] = netLoss;
    out[2] = mapLoss;
    out[3] = a2 / (float)(NR * MM);
    out[4] = a3 / a4;
  }
}

extern "C" void kernel_launch(void* const* d_in, const int* in_sizes, int n_in,
                              void* d_out, int out_size, void* d_ws, size_t ws_size,
                              hipStream_t stream) {
  const float* x = (const float*)d_in[0];
  const int* y = (const int*)d_in[1];
  const float* centroids = (const float*)d_in[2];
  const int* perm = (const int*)d_in[3];
  const void* tmap = d_in[4];
  const void* traw = d_in[5];
  const float* W1 = (const float*)d_in[6];
  const float* B1 = (const float*)d_in[7];
  const float* W2 = (const float*)d_in[8];
  const float* B2 = (const float*)d_in[9];
  float* out = (float*)d_out;

  char* w = (char*)d_ws;
  float* accbuf = (float*)w;                                  // 128 slots x 8 floats = 4 KB
  uint32_t* xp16 = (uint32_t*)(w + 4096);                     // 4 MB (fp16 pairs)
  uint32_t* xm16 = xp16 + (size_t)NR * 32;                    // 4 MB
  ull* targ = (ull*)(xm16 + (size_t)NR * 32);                 // 256 KB
  ull* cb64 = targ + NR;                                      // 1 KB (128 slots)
  ull* xb = cb64 + 128;                                       // 256 KB
  float* winv = (float*)(xb + NR);                            // 128 KB
  int* nposA = (int*)(winv + NR);                             // 128 KB
  unsigned char* poslist = (unsigned char*)(nposA + NR);      // 2 MB
  _Float16* Wp = (_Float16*)(poslist + (size_t)NR * 64);      // 1 MB (fp16 frags)
  _Float16* Wp1 = Wp + (1 << 19);                             // 128 KB (L1 frags)
  float* B2s = (float*)(Wp1 + (1 << 16));                     // 8 KB (B2 * log2e)

  hipMemsetAsync(accbuf, 0, 4096, stream);

  // jax.random.key(1) -> (0,1); split -> kmap=(w0(0,2), w0(1,3)), kraw=(w1(0,2), w1(1,3))
  uint32_t a0, b0, a1, b1;
  tf2x32(0u, 1u, 0u, 2u, a0, b0);
  tf2x32(0u, 1u, 1u, 3u, a1, b1);

  stage1p<<<2048 + 314, 256, 0, stream>>>(x, y, perm, tmap, traw, a0, a1, b0, b1,
                                          W2, W1, B1, B2, centroids, Wp, Wp1, B2s, cb64,
                                          xp16, xm16, targ, xb, winv, poslist, nposA);
  dim3 g(NR / 64, MM, 3);
  mapnet8<<<g, 512, 0, stream>>>(xm16, xp16, Wp1, Wp, B2s, targ, winv, poslist, nposA,
                                 cb64, xb, accbuf);
  finalk<<<1, 128, 0, stream>>>(accbuf, out);
}

// Round 5
// 214.411 us; speedup vs baseline: 1.2411x; 1.2411x over previous
//
#include <hip/hip_runtime.h>
#include <stdint.h>

#define NR 32768
#define MM 8
#define NCLS 100
#define HALFN 1048576u
#define HSS 260   // fp16 stride for h plane rows (R1/R2-measured low-conflict with b64 ops)
#define LGS 260   // float stride for logit rows (aliases h exactly)
#define PSS 12    // float stride for per-row partial arrays

#define LOG2E 1.4426950408889634f
#define LN2F  0.6931471805599453f

typedef _Float16 h8 __attribute__((ext_vector_type(8)));
typedef _Float16 h4 __attribute__((ext_vector_type(4)));
typedef float f4 __attribute__((ext_vector_type(4)));
typedef unsigned long long ull;

// ---------------- threefry2x32 (exact JAX semantics) ----------------
__host__ __device__ inline void tf2x32(uint32_t k0, uint32_t k1, uint32_t x0, uint32_t x1,
                                       uint32_t& o0, uint32_t& o1) {
  uint32_t ks0 = k0, ks1 = k1, ks2 = k0 ^ k1 ^ 0x1BD11BDAu;
  x0 += ks0; x1 += ks1;
#define TFR(r) { x0 += x1; x1 = (x1 << r) | (x1 >> (32 - r)); x1 ^= x0; }
  TFR(13) TFR(15) TFR(26) TFR(6)  x0 += ks1; x1 += ks2 + 1u;
  TFR(17) TFR(29) TFR(16) TFR(24) x0 += ks2; x1 += ks0 + 2u;
  TFR(13) TFR(15) TFR(26) TFR(6)  x0 += ks0; x1 += ks1 + 3u;
  TFR(17) TFR(29) TFR(16) TFR(24) x0 += ks1; x1 += ks2 + 4u;
  TFR(13) TFR(15) TFR(26) TFR(6)  x0 += ks2; x1 += ks0 + 5u;
#undef TFR
  o0 = x0; o1 = x1;
}

// template dtype auto-detect: float32 {0,1.0f} / int32 {0,1} / bytes. 4 ones expected.
__device__ inline int load_tmpl(const void* p, int lane) {
  const unsigned* pi = (const unsigned*)p;
  unsigned w = pi[lane];
  ull okF = __ballot(w == 0u || w == 0x3F800000u);
  ull onF = __ballot(w == 0x3F800000u);
  ull okI = __ballot(w <= 1u);
  ull onI = __ballot(w == 1u);
  if (okF == ~0ull && __popcll(onF) == 4) return (w == 0x3F800000u) ? 1 : 0;
  if (okI == ~0ull && __popcll(onI) == 4) return (int)w;
  const unsigned char* pb = (const unsigned char*)p;
  return pb[lane] ? 1 : 0;
}

__device__ inline uint32_t packh2(float a, float b) {
  union { _Float16 h[2]; uint32_t u; } cv;
  cv.h[0] = (_Float16)a; cv.h[1] = (_Float16)b;
  return cv.u;
}

// flip mask from template ballot: for each of the 4 template-one positions p,
// set bit rank(p) where rank = #{keys < key_p}. Keys are unique (lane in low bits),
// so this equals the stable-argsort rank; identical to the old O(64^2) path.
__device__ inline ull flip_mask(ull tmask, uint32_t key) {
  ull fm = 0;
  while (tmask) {
    int p = __ffsll((long long)tmask) - 1;
    tmask &= tmask - 1;
    uint32_t kp = (uint32_t)__builtin_amdgcn_readlane((int)key, p);
    fm |= 1ull << __popcll(__ballot(key < kp));
  }
  return fm;
}

// ---------------- stage1p: per-row transform + weight prep fused ----------------
// blocks 0..2047: 16 rows/block, 4 rows/wave {b*8+wv*2, +1, +16384, +16385}.
// Each wave computes BOTH threefry keys for its own row-pairs and consumes both
// outputs of each tf2x32 in-register -> no LDS exchange, no barrier.
// blocks 2048..2303: W2 frag pack; 2304..2335: W1+B1 frag pack (x log2e, bias on
// K-slot 8); 2336..2360: cb64; 2361: B2s = B2 * log2e.
__global__ __launch_bounds__(256) void stage1p(
    const float* __restrict__ x, const int* __restrict__ y, const int* __restrict__ perm,
    const void* tmap, const void* traw,
    uint32_t km0, uint32_t km1, uint32_t kr0, uint32_t kr1,
    const float* __restrict__ W2, const float* __restrict__ W1,
    const float* __restrict__ B1, const float* __restrict__ B2,
    const float* __restrict__ centroids,
    _Float16* __restrict__ Wp, _Float16* __restrict__ Wp1, float* __restrict__ B2s,
    ull* __restrict__ cb64,
    uint32_t* __restrict__ xp16, uint32_t* __restrict__ xm16,
    ull* __restrict__ targ, ull* __restrict__ xb,
    float* __restrict__ winv, unsigned char* __restrict__ poslist, int* __restrict__ nposA) {
  int b = blockIdx.x, tid = threadIdx.x;
  if (b >= 2048) {
    int pb = b - 2048;
    if (pb < 256) {
      // W2: gid = ((m*8+kt)*16+NT)*64 + q*16+lr ; elem j = W2[m][kt*32+q*8+j][NT*16+lr]
      int gid = pb * 256 + tid;
      int lane6 = gid & 63, frag = gid >> 6;
      int NT = frag & 15, kt = (frag >> 4) & 7, m = frag >> 7;
      int q = lane6 >> 4, lr = lane6 & 15;
      const float* src = W2 + (size_t)m * 65536 + (size_t)(kt * 32 + q * 8) * 256 + NT * 16 + lr;
      h8 v;
#pragma unroll
      for (int j = 0; j < 8; j++) v[j] = (_Float16)src[j * 256];
      *(h8*)(Wp + (size_t)gid * 8) = v;
    } else if (pb < 288) {
      // W1 frag (m, t), scaled by log2e: lane(q,lr) j -> A[hid=t*16+lr][k=q*8+j]:
      // q0 = W1[j][hid]*log2e; (q1,j0) = B1[hid]*log2e (bias rides K-slot 8); else 0
      int idx = (pb - 256) * 256 + tid;  // 8192 total
      int lane = idx & 63, t = (idx >> 6) & 15, m = idx >> 10;
      int q = lane >> 4, lr = lane & 15;
      h8 v;
#pragma unroll
      for (int j = 0; j < 8; j++) {
        float val = 0.0f;
        if (q == 0) val = W1[(size_t)(m * 8 + j) * 256 + t * 16 + lr] * LOG2E;
        else if (q == 1 && j == 0) val = B1[m * 256 + t * 16 + lr] * LOG2E;
        v[j] = (_Float16)val;
      }
      *(h8*)(Wp1 + (size_t)idx * 8) = v;
    } else if (pb < 313) {
      // centroid bits: 4 classes per block, one wave each (25 blocks x 4 = 100)
      int c = (pb - 288) * 4 + (tid >> 6);
      int lane = tid & 63;
      ull bits = __ballot(centroids[c * 64 + perm[lane]] > 0.0f);
      if (lane == 0 && c < NCLS) cb64[c] = bits;
    } else {
      // B2s = B2 * log2e (2048 floats)
#pragma unroll
      for (int j = 0; j < 8; j++) B2s[tid * 8 + j] = B2[tid * 8 + j] * LOG2E;
    }
    return;
  }

  int wv = tid >> 6, lane = tid & 63;
  int tm = load_tmpl(tmap, lane);
  int tr = load_tmpl(traw, lane);
  ull tmm = __ballot(tm != 0);
  ull trm = __ballot(tr != 0);
  int pv = perm[lane];

  int nbase = b * 8 + wv * 2;  // < 16384
  uint32_t bmv[4], brv[4];
  {
    uint32_t iA = (uint32_t)(nbase * 64 + lane);
    uint32_t iB = iA + 64u;
    tf2x32(km0, km1, iA, iA + HALFN, bmv[0], bmv[2]);
    tf2x32(kr0, kr1, iA, iA + HALFN, brv[0], brv[2]);
    tf2x32(km0, km1, iB, iB + HALFN, bmv[1], bmv[3]);
    tf2x32(kr0, kr1, iB, iB + HALFN, brv[1], brv[3]);
  }
  const int nn[4] = {nbase, nbase + 1, nbase + 16384, nbase + 16385};
#pragma unroll
  for (int rr = 0; rr < 4; rr++) {
    int n = nn[rr];
    float xpv = x[(size_t)n * 64 + pv];
    // rank key: ((bits>>9)<<6)|lane == stable argsort key of the uniform (unique)
    uint32_t kmk = ((bmv[rr] >> 9) << 6) | (uint32_t)lane;
    uint32_t krk = ((brv[rr] >> 9) << 6) | (uint32_t)lane;
    ull fm = flip_mask(tmm, kmk);
    ull fr = flip_mask(trm, krk);
    float xmv = ((fm >> lane) & 1ull) ? -xpv : xpv;
    float rfv = ((fr >> lane) & 1ull) ? -xpv : xpv;
    // fp16 outputs (identical rounding to former in-kernel cvt)
    float xp_o = __shfl_xor(xpv, 1);
    float xm_o = __shfl_xor(xmv, 1);
    if ((lane & 1) == 0) {
      xp16[n * 32 + (lane >> 1)] = packh2(xpv, xp_o);
      xm16[n * 32 + (lane >> 1)] = packh2(xmv, xm_o);
    }
    ull t64 = __ballot(rfv > 0.0f);
    ull b64v = __ballot(xpv > 0.0f);

    int c1 = y[(size_t)n * NCLS + lane] > 0;
    int c2 = (lane < NCLS - 64) ? (y[(size_t)n * NCLS + 64 + lane] > 0) : 0;
    ull p0 = __ballot(c1);
    ull p1 = __ballot(c2);
    int cnt0 = __popcll(p0);
    float cnt = (float)(cnt0 + __popcll(p1));

    unsigned char* pl = poslist + (size_t)n * 64;
    ull below = (lane == 0) ? 0ull : (~0ull >> (64 - lane));
    if (c1) pl[__popcll(p0 & below)] = (unsigned char)lane;
    if (c2) pl[cnt0 + __popcll(p1 & below)] = (unsigned char)(64 + lane);

    if (lane == 0) {
      targ[n] = t64;
      xb[n] = b64v;
      winv[n] = 1.0f / cnt;
      nposA[n] = cnt0 + __popcll(p1);
    }
  }
}

// ---------------- fused MLP + loss epilogue + hamming slice ----
// grid (512, 8, 3); block 512 (8 waves). z0 = map, z1 = net, z2 = hamming.
// ALL LDS accesses <= 64-bit: measured R1-R4 ladder shows wave64 b128 LDS ops
// serialize ~4x on this access shape regardless of add/XOR swizzle (conflicts
// 4.4M b64-only -> 15.3M +b128-writes -> 59.3M +b128-reads, identical under
// swizzle). h-plane: HSS=260, h4 writes, h4 lo/hi reads (R1/R2-measured).
// Swapped mfma operands: acc reg-dim walks COLUMNS; bias preloaded into acc.
// Pass 0: no logit staging; lse/max from ps/pm partials; picked/hit extracted
// at the owner lane. Pass 1 stages logits via b32 stores for the poslist gather.
__global__ __launch_bounds__(512, 8) void mapnet8(
    const uint32_t* __restrict__ Xm16, const uint32_t* __restrict__ Xp16,
    const _Float16* __restrict__ Wp1, const _Float16* __restrict__ Wp,
    const float* __restrict__ B2s,
    const ull* __restrict__ targ, const float* __restrict__ winv,
    const unsigned char* __restrict__ poslist, const int* __restrict__ nposA,
    const ull* __restrict__ cb64, const ull* __restrict__ xb,
    float* __restrict__ accbuf) {
  __shared__ union {
    _Float16 h[64 * HSS];      // fp16 h-plane, 33280 B
    float lg[32 * LGS];        // logit staging, 33280 B (exact alias)
  } u;
  __shared__ float ps[64 * PSS];   // per-row exp2-sum partials [row][wv]
  __shared__ float pm[64 * PSS];   // per-row max partials (pass 0)
  __shared__ float mvA[64];        // combined per-row max (pass 0)
  __shared__ int   tA[64];         // per-row target byte (pass 0)
  __shared__ float sl[3];          // block accumulators
  const int tid = threadIdx.x, lane = tid & 63, wv = tid >> 6;
  const int q = lane >> 4, lr = lane & 15;
  const int m = blockIdx.y, pass = blockIdx.z;
  const int n0 = blockIdx.x * 64;
  if (tid < 3) sl[tid] = 0.0f;

  if (pass == 2) {
    // hamming + cnt: 8 rows per block (one per wave)
    __syncthreads();
    int flat = blockIdx.y * 512 + blockIdx.x;   // 0..4095
    int n = flat * 8 + wv;
    ull xv = xb[n];
    float px = (float)__popcll(xv);
    int np = nposA[n];
    float hs = 0.0f;
    if (lane < np) {
      int c = poslist[(size_t)n * 64 + lane];
      ull cb = cb64[c];
      hs = px + (float)__popcll(cb) - 2.0f * (float)__popcll(xv & cb);
    }
#pragma unroll
    for (int off = 1; off < 64; off <<= 1) hs += __shfl_xor(hs, off);
    if (lane == 0) {
      atomicAdd(&sl[0], hs);
      atomicAdd(&sl[1], (float)np);
    }
    __syncthreads();
    if (tid == 0) {
      float* slot = accbuf + (flat & 127) * 8;
      atomicAdd(&slot[3], sl[0]);
      atomicAdd(&slot[4], sl[1]);
    }
    return;
  }

  const uint32_t* Xin = pass ? Xp16 : Xm16;

  // ---- L1 (transposed): wave wv covers rowblock rb = wv&3, t-range (wv>>2)*8..+7
  // W1/B1 pre-scaled by log2e; bias rides K-slot 8 (af[0]=1 on q==1 lanes).
  const int rb = wv & 3, tbase = (wv >> 2) * 8;
  h8 af;
  {
    const _Float16* xsrc = (const _Float16*)(Xin + (size_t)(n0 + rb * 16 + lr) * 32) + m * 8;
    h8 xv = *(const h8*)xsrc;
    h8 zero = {(_Float16)0.0f, (_Float16)0.0f, (_Float16)0.0f, (_Float16)0.0f,
               (_Float16)0.0f, (_Float16)0.0f, (_Float16)0.0f, (_Float16)0.0f};
    af = (q == 0) ? xv : zero;
    if (q == 1) af[0] = (_Float16)1.0f;
  }
#pragma unroll 4
  for (int tt = 0; tt < 8; tt++) {
    int t = tbase + tt;
    h8 wfrag = *(const h8*)(Wp1 + ((size_t)(m * 16 + t) * 64 + lane) * 8);
    f4 z = __builtin_amdgcn_mfma_f32_16x16x32_f16(wfrag, af, (f4){0.f, 0.f, 0.f, 0.f}, 0, 0, 0);
    h4 pk;
#pragma unroll
    for (int reg = 0; reg < 4; reg++) {
      float z2 = z[reg];  // (z+b1)*log2e
      // silu*log2e = z2 * rcp(1 + exp2(-z2)); neg is a free input modifier
      pk[reg] = (_Float16)(z2 * __builtin_amdgcn_rcpf(1.0f + __builtin_amdgcn_exp2f(-z2)));
    }
    *(h4*)(u.h + (size_t)(rb * 16 + lr) * HSS + t * 16 + q * 4) = pk;
  }
  __syncthreads();

  // ---- K loop (swapped operands): acc4[rt][nt][reg] =
  //      logit2[n = rt*16+lr][col = wv*32 + nt*16 + q*4 + reg], bias pre-loaded ----
  f4 acc4[4][2];
  {
    f4 bv0 = *(const f4*)(B2s + m * 256 + wv * 32 + q * 4);
    f4 bv1 = *(const f4*)(B2s + m * 256 + wv * 32 + 16 + q * 4);
#pragma unroll
    for (int rt = 0; rt < 4; rt++) { acc4[rt][0] = bv0; acc4[rt][1] = bv1; }
  }
  const size_t wbase = (size_t)m * 65536;
#pragma unroll 2
  for (int kt = 0; kt < 8; kt++) {
    h8 bh0 = *(const h8*)(Wp + wbase + (((size_t)kt * 16 + wv * 2 + 0) * 64 + lane) * 8);
    h8 bh1 = *(const h8*)(Wp + wbase + (((size_t)kt * 16 + wv * 2 + 1) * 64 + lane) * 8);
#pragma unroll
    for (int rt = 0; rt < 4; rt++) {
      // two b64 LDS reads + merge (measured low-conflict; b128 serializes ~4x)
      const _Float16* p = u.h + (size_t)(rt * 16 + lr) * HSS + kt * 32 + q * 8;
      h4 lo = *(const h4*)p;
      h4 hi = *(const h4*)(p + 4);
      h8 ah = __builtin_shufflevector(lo, hi, 0, 1, 2, 3, 4, 5, 6, 7);
      acc4[rt][0] = __builtin_amdgcn_mfma_f32_16x16x32_f16(bh0, ah, acc4[rt][0], 0, 0, 0);
      acc4[rt][1] = __builtin_amdgcn_mfma_f32_16x16x32_f16(bh1, ah, acc4[rt][1], 0, 0, 0);
    }
  }

  // ---- in-register softmax partials: row rt*16+lr, this wave's 32 cols ----
  float rsum[4], rmax[4];
#pragma unroll
  for (int rt = 0; rt < 4; rt++) {
    f4 l0 = acc4[rt][0], l1 = acc4[rt][1];
    float s = 0.0f;
#pragma unroll
    for (int reg = 0; reg < 4; reg++)
      s += __builtin_amdgcn_exp2f(l0[reg]) + __builtin_amdgcn_exp2f(l1[reg]);
    rsum[rt] = s;
    if (pass == 0) {
      float mv = fmaxf(l0[0], l1[0]);
#pragma unroll
      for (int reg = 1; reg < 4; reg++) mv = fmaxf(mv, fmaxf(l0[reg], l1[reg]));
      rmax[rt] = mv;
    }
  }
#pragma unroll
  for (int rt = 0; rt < 4; rt++) {
    rsum[rt] += __shfl_xor(rsum[rt], 16);
    rsum[rt] += __shfl_xor(rsum[rt], 32);
  }
  if (pass == 0) {
#pragma unroll
    for (int rt = 0; rt < 4; rt++) {
      rmax[rt] = fmaxf(rmax[rt], __shfl_xor(rmax[rt], 16));
      rmax[rt] = fmaxf(rmax[rt], __shfl_xor(rmax[rt], 32));
    }
  }
  if (lane < 16) {
#pragma unroll
    for (int rt = 0; rt < 4; rt++) {
      ps[(rt * 16 + lane) * PSS + wv] = rsum[rt];
      if (pass == 0) pm[(rt * 16 + lane) * PSS + wv] = rmax[rt];
    }
  }

  if (pass == 0) {
    // ---- owner-lane extraction: no logit staging ----
    __syncthreads();
    float myLse = 0.0f;
    if (tid < 64) {
      int row = tid, n = n0 + row;
      f4 s0 = *(const f4*)(ps + row * PSS);
      f4 s1 = *(const f4*)(ps + row * PSS + 4);
      f4 ss = s0 + s1;
      float s = (ss[0] + ss[1]) + (ss[2] + ss[3]);
      f4 m0 = *(const f4*)(pm + row * PSS);
      f4 m1 = *(const f4*)(pm + row * PSS + 4);
      float mv = fmaxf(fmaxf(fmaxf(m0[0], m0[1]), fmaxf(m0[2], m0[3])),
                       fmaxf(fmaxf(m1[0], m1[1]), fmaxf(m1[2], m1[3])));
      mvA[row] = mv;
      tA[row] = (int)((targ[n] >> (m * 8)) & 0xFFull);
      myLse = __builtin_amdgcn_logf(s);   // base-2 lse (bias already in logits)
    }
    __syncthreads();
    float pick = 0.0f, hit = 0.0f;
    const int cbase = wv * 32 + q * 4;
#pragma unroll
    for (int rt = 0; rt < 4; rt++) {
      int row = rt * 16 + lr;
      int d0 = tA[row] - cbase;           // LDS broadcast read
#pragma unroll
      for (int nt = 0; nt < 2; nt++) {
        int d = d0 - nt * 16;
        if ((unsigned)d < 4u) {
          f4 f = acc4[rt][nt];
          float v = f[0];
          v = (d == 1) ? f[1] : v;
          v = (d == 2) ? f[2] : v;
          v = (d == 3) ? f[3] : v;
          pick += v;
          hit += (v == mvA[row]) ? 1.0f : 0.0f;
        }
      }
    }
    float lossC = myLse - pick;
#pragma unroll
    for (int off = 1; off < 64; off <<= 1) {
      lossC += __shfl_xor(lossC, off);
      hit += __shfl_xor(hit, off);
    }
    if (lane == 0) {
      atomicAdd(&sl[0], lossC);
      atomicAdd(&sl[2], hit);
    }
  } else {
    // ---- pass 1: stage logits (b32 stores) for the poslist gather; two 32-row phases ----
    float partLoss = 0.0f;
    for (int ph = 0; ph < 2; ph++) {
      __syncthreads();
#pragma unroll
      for (int rt2 = 0; rt2 < 2; rt2++) {
#pragma unroll
        for (int nt = 0; nt < 2; nt++)
#pragma unroll
          for (int reg = 0; reg < 4; reg++)
            u.lg[(rt2 * 16 + lr) * LGS + wv * 32 + nt * 16 + q * 4 + reg] =
                acc4[ph * 2 + rt2][nt][reg];
      }
      __syncthreads();
      int rl = tid >> 4;                   // local row 0..31
      int grow = ph * 32 + rl;             // row within block
      int n = n0 + grow;
      int cl = tid & 15;
      const float* lrow = u.lg + rl * LGS;
      int np = nposA[n];
      const unsigned char* pl = poslist + (size_t)n * 64;
      float sp = 0.0f;
      for (int j2 = cl; j2 < np; j2 += 16) {
        int c = pl[j2];
        int t = (int)((cb64[c] >> (m * 8)) & 0xFFull);
        sp += lrow[t];
      }
#pragma unroll
      for (int off = 1; off < 16; off <<= 1) sp += __shfl_xor(sp, off);
      if (cl == 0) {
        f4 s0 = *(const f4*)(ps + grow * PSS);
        f4 s1 = *(const f4*)(ps + grow * PSS + 4);
        f4 ss = s0 + s1;
        float s = (ss[0] + ss[1]) + (ss[2] + ss[3]);
        partLoss += __builtin_amdgcn_logf(s) - winv[n] * sp;
      }
    }
    partLoss += __shfl_xor(partLoss, 16);
    partLoss += __shfl_xor(partLoss, 32);
    if (lane == 0) atomicAdd(&sl[1], partLoss);
  }

  __syncthreads();
  if (tid == 0) {
    float* slot = accbuf + (blockIdx.x & 127) * 8;
    if (pass == 0) {
      atomicAdd(&slot[0], sl[0]);
      atomicAdd(&slot[2], sl[2]);
    } else {
      atomicAdd(&slot[1], sl[1]);
    }
  }
}

__global__ __launch_bounds__(128) void finalk(const float* __restrict__ accbuf, float* __restrict__ out) {
  int t = threadIdx.x;  // 0..127
  float v0 = accbuf[t * 8 + 0], v1 = accbuf[t * 8 + 1], v2 = accbuf[t * 8 + 2];
  float v3 = accbuf[t * 8 + 3], v4 = accbuf[t * 8 + 4];
#pragma unroll
  for (int off = 1; off < 64; off <<= 1) {
    v0 += __shfl_xor(v0, off); v1 += __shfl_xor(v1, off); v2 += __shfl_xor(v2, off);
    v3 += __shfl_xor(v3, off); v4 += __shfl_xor(v4, off);
  }
  __shared__ float s[2][5];
  if ((t & 63) == 0) {
    s[t >> 6][0] = v0; s[t >> 6][1] = v1; s[t >> 6][2] = v2; s[t >> 6][3] = v3; s[t >> 6][4] = v4;
  }
  __syncthreads();
  if (t == 0) {
    float a0 = s[0][0] + s[1][0], a1 = s[0][1] + s[1][1], a2 = s[0][2] + s[1][2];
    float a3 = s[0][3] + s[1][3], a4 = s[0][4] + s[1][4];
    // losses accumulated in base-2 (exp2-domain logits): scale back by ln2 here.
    float netLoss = a1 * LN2F / (float)NR;
    float mapLoss = a0 * LN2F / (float)NR;
    out[0] = netLoss + mapLoss;
    out[1] = netLoss;
    out[2] = mapLoss;
    out[3] = a2 / (float)(NR * MM);
    out[4] = a3 / a4;
  }
}

extern "C" void kernel_launch(void* const* d_in, const int* in_sizes, int n_in,
                              void* d_out, int out_size, void* d_ws, size_t ws_size,
                              hipStream_t stream) {
  const float* x = (const float*)d_in[0];
  const int* y = (const int*)d_in[1];
  const float* centroids = (const float*)d_in[2];
  const int* perm = (const int*)d_in[3];
  const void* tmap = d_in[4];
  const void* traw = d_in[5];
  const float* W1 = (const float*)d_in[6];
  const float* B1 = (const float*)d_in[7];
  const float* W2 = (const float*)d_in[8];
  const float* B2 = (const float*)d_in[9];
  float* out = (float*)d_out;

  char* w = (char*)d_ws;
  float* accbuf = (float*)w;                                  // 128 slots x 8 floats = 4 KB
  uint32_t* xp16 = (uint32_t*)(w + 4096);                     // 4 MB (fp16 pairs)
  uint32_t* xm16 = xp16 + (size_t)NR * 32;                    // 4 MB
  ull* targ = (ull*)(xm16 + (size_t)NR * 32);                 // 256 KB
  ull* cb64 = targ + NR;                                      // 1 KB (128 slots)
  ull* xb = cb64 + 128;                                       // 256 KB
  float* winv = (float*)(xb + NR);                            // 128 KB
  int* nposA = (int*)(winv + NR);                             // 128 KB
  unsigned char* poslist = (unsigned char*)(nposA + NR);      // 2 MB
  _Float16* Wp = (_Float16*)(poslist + (size_t)NR * 64);      // 1 MB (fp16 frags)
  _Float16* Wp1 = Wp + (1 << 19);                             // 128 KB (L1 frags)
  float* B2s = (float*)(Wp1 + (1 << 16));                     // 8 KB (B2 * log2e)

  hipMemsetAsync(accbuf, 0, 4096, stream);

  // jax.random.key(1) -> (0,1); split -> kmap=(w0(0,2), w0(1,3)), kraw=(w1(0,2), w1(1,3))
  uint32_t a0, b0, a1, b1;
  tf2x32(0u, 1u, 0u, 2u, a0, b0);
  tf2x32(0u, 1u, 1u, 3u, a1, b1);

  stage1p<<<2048 + 314, 256, 0, stream>>>(x, y, perm, tmap, traw, a0, a1, b0, b1,
                                          W2, W1, B1, B2, centroids, Wp, Wp1, B2s, cb64,
                                          xp16, xm16, targ, xb, winv, poslist, nposA);
  dim3 g(NR / 64, MM, 3);
  mapnet8<<<g, 512, 0, stream>>>(xm16, xp16, Wp1, Wp, B2s, targ, winv, poslist, nposA,
                                 cb64, xb, accbuf);
  finalk<<<1, 128, 0, stream>>>(accbuf, out);
}

// Round 6
// 211.973 us; speedup vs baseline: 1.2553x; 1.0115x over previous
//
#include <hip/hip_runtime.h>
#include <stdint.h>

#define NR 32768
#define MM 8
#define NCLS 100
#define HALFN 1048576u
#define HSS 260   // fp16 stride for h plane rows (R1/R2/R5-measured low-conflict with b64 ops)
#define LGS 260   // float stride for logit rows (aliases h exactly)
#define PSS 12    // float stride for per-row partial arrays

#define LOG2E 1.4426950408889634f
#define LN2F  0.6931471805599453f

typedef _Float16 h8 __attribute__((ext_vector_type(8)));
typedef _Float16 h4 __attribute__((ext_vector_type(4)));
typedef float f4 __attribute__((ext_vector_type(4)));
typedef unsigned long long ull;

// ---------------- threefry2x32 (exact JAX semantics) ----------------
__host__ __device__ inline void tf2x32(uint32_t k0, uint32_t k1, uint32_t x0, uint32_t x1,
                                       uint32_t& o0, uint32_t& o1) {
  uint32_t ks0 = k0, ks1 = k1, ks2 = k0 ^ k1 ^ 0x1BD11BDAu;
  x0 += ks0; x1 += ks1;
#define TFR(r) { x0 += x1; x1 = (x1 << r) | (x1 >> (32 - r)); x1 ^= x0; }
  TFR(13) TFR(15) TFR(26) TFR(6)  x0 += ks1; x1 += ks2 + 1u;
  TFR(17) TFR(29) TFR(16) TFR(24) x0 += ks2; x1 += ks0 + 2u;
  TFR(13) TFR(15) TFR(26) TFR(6)  x0 += ks0; x1 += ks1 + 3u;
  TFR(17) TFR(29) TFR(16) TFR(24) x0 += ks1; x1 += ks2 + 4u;
  TFR(13) TFR(15) TFR(26) TFR(6)  x0 += ks2; x1 += ks0 + 5u;
#undef TFR
  o0 = x0; o1 = x1;
}

// template dtype auto-detect: float32 {0,1.0f} / int32 {0,1} / bytes. 4 ones expected.
__device__ inline int load_tmpl(const void* p, int lane) {
  const unsigned* pi = (const unsigned*)p;
  unsigned w = pi[lane];
  ull okF = __ballot(w == 0u || w == 0x3F800000u);
  ull onF = __ballot(w == 0x3F800000u);
  ull okI = __ballot(w <= 1u);
  ull onI = __ballot(w == 1u);
  if (okF == ~0ull && __popcll(onF) == 4) return (w == 0x3F800000u) ? 1 : 0;
  if (okI == ~0ull && __popcll(onI) == 4) return (int)w;
  const unsigned char* pb = (const unsigned char*)p;
  return pb[lane] ? 1 : 0;
}

__device__ inline uint32_t packh2(float a, float b) {
  union { _Float16 h[2]; uint32_t u; } cv;
  cv.h[0] = (_Float16)a; cv.h[1] = (_Float16)b;
  return cv.u;
}

// flip mask from template ballot: for each of the 4 template-one positions p,
// set bit rank(p) where rank = #{keys < key_p}. Keys are unique (lane in low bits),
// so this equals the stable-argsort rank; identical to the old O(64^2) path.
__device__ inline ull flip_mask(ull tmask, uint32_t key) {
  ull fm = 0;
  while (tmask) {
    int p = __ffsll((long long)tmask) - 1;
    tmask &= tmask - 1;
    uint32_t kp = (uint32_t)__builtin_amdgcn_readlane((int)key, p);
    fm |= 1ull << __popcll(__ballot(key < kp));
  }
  return fm;
}

// ---------------- stage1p: per-row transform + weight prep fused ----------------
// blocks 0..2047: 16 rows/block, 4 rows/wave {b*8+wv*2, +1, +16384, +16385}.
// Each wave computes BOTH threefry keys for its own row-pairs and consumes both
// outputs of each tf2x32 in-register -> no LDS exchange, no barrier.
// x/y loads for all 4 rows are hoisted ahead of the ballot-bearing loop so the
// 4 HBM latencies overlap (convergent ops block compiler hoisting).
// blocks 2048..2303: W2 frag pack; 2304..2335: W1+B1 frag pack (x log2e, bias on
// K-slot 8); 2336..2360: cb64; 2361: B2s = B2 * log2e.
__global__ __launch_bounds__(256) void stage1p(
    const float* __restrict__ x, const int* __restrict__ y, const int* __restrict__ perm,
    const void* tmap, const void* traw,
    uint32_t km0, uint32_t km1, uint32_t kr0, uint32_t kr1,
    const float* __restrict__ W2, const float* __restrict__ W1,
    const float* __restrict__ B1, const float* __restrict__ B2,
    const float* __restrict__ centroids,
    _Float16* __restrict__ Wp, _Float16* __restrict__ Wp1, float* __restrict__ B2s,
    ull* __restrict__ cb64,
    uint32_t* __restrict__ xp16, uint32_t* __restrict__ xm16,
    ull* __restrict__ targ, ull* __restrict__ xb,
    float* __restrict__ winv, unsigned char* __restrict__ poslist, int* __restrict__ nposA) {
  int b = blockIdx.x, tid = threadIdx.x;
  if (b >= 2048) {
    int pb = b - 2048;
    if (pb < 256) {
      // W2: gid = ((m*8+kt)*16+NT)*64 + q*16+lr ; elem j = W2[m][kt*32+q*8+j][NT*16+lr]
      int gid = pb * 256 + tid;
      int lane6 = gid & 63, frag = gid >> 6;
      int NT = frag & 15, kt = (frag >> 4) & 7, m = frag >> 7;
      int q = lane6 >> 4, lr = lane6 & 15;
      const float* src = W2 + (size_t)m * 65536 + (size_t)(kt * 32 + q * 8) * 256 + NT * 16 + lr;
      h8 v;
#pragma unroll
      for (int j = 0; j < 8; j++) v[j] = (_Float16)src[j * 256];
      *(h8*)(Wp + (size_t)gid * 8) = v;
    } else if (pb < 288) {
      // W1 frag (m, t), scaled by log2e: lane(q,lr) j -> A[hid=t*16+lr][k=q*8+j]:
      // q0 = W1[j][hid]*log2e; (q1,j0) = B1[hid]*log2e (bias rides K-slot 8); else 0
      int idx = (pb - 256) * 256 + tid;  // 8192 total
      int lane = idx & 63, t = (idx >> 6) & 15, m = idx >> 10;
      int q = lane >> 4, lr = lane & 15;
      h8 v;
#pragma unroll
      for (int j = 0; j < 8; j++) {
        float val = 0.0f;
        if (q == 0) val = W1[(size_t)(m * 8 + j) * 256 + t * 16 + lr] * LOG2E;
        else if (q == 1 && j == 0) val = B1[m * 256 + t * 16 + lr] * LOG2E;
        v[j] = (_Float16)val;
      }
      *(h8*)(Wp1 + (size_t)idx * 8) = v;
    } else if (pb < 313) {
      // centroid bits: 4 classes per block, one wave each (25 blocks x 4 = 100)
      int c = (pb - 288) * 4 + (tid >> 6);
      int lane = tid & 63;
      ull bits = __ballot(centroids[c * 64 + perm[lane]] > 0.0f);
      if (lane == 0 && c < NCLS) cb64[c] = bits;
    } else {
      // B2s = B2 * log2e (2048 floats)
#pragma unroll
      for (int j = 0; j < 8; j++) B2s[tid * 8 + j] = B2[tid * 8 + j] * LOG2E;
    }
    return;
  }

  int wv = tid >> 6, lane = tid & 63;
  int tm = load_tmpl(tmap, lane);
  int tr = load_tmpl(traw, lane);
  ull tmm = __ballot(tm != 0);
  ull trm = __ballot(tr != 0);
  int pv = perm[lane];

  int nbase = b * 8 + wv * 2;  // < 16384
  uint32_t bmv[4], brv[4];
  {
    uint32_t iA = (uint32_t)(nbase * 64 + lane);
    uint32_t iB = iA + 64u;
    tf2x32(km0, km1, iA, iA + HALFN, bmv[0], bmv[2]);
    tf2x32(kr0, kr1, iA, iA + HALFN, brv[0], brv[2]);
    tf2x32(km0, km1, iB, iB + HALFN, bmv[1], bmv[3]);
    tf2x32(kr0, kr1, iB, iB + HALFN, brv[1], brv[3]);
  }
  const int nn[4] = {nbase, nbase + 1, nbase + 16384, nbase + 16385};
  // hoisted loads: all 4 rows' x and y issue together (overlapped HBM latency)
  float xr[4];
  int yv1[4], yv2[4];
#pragma unroll
  for (int rr = 0; rr < 4; rr++) {
    int n = nn[rr];
    xr[rr] = x[(size_t)n * 64 + pv];
    yv1[rr] = y[(size_t)n * NCLS + lane];
    yv2[rr] = (lane < NCLS - 64) ? y[(size_t)n * NCLS + 64 + lane] : 0;
  }
#pragma unroll
  for (int rr = 0; rr < 4; rr++) {
    int n = nn[rr];
    float xpv = xr[rr];
    // rank key: ((bits>>9)<<6)|lane == stable argsort key of the uniform (unique)
    uint32_t kmk = ((bmv[rr] >> 9) << 6) | (uint32_t)lane;
    uint32_t krk = ((brv[rr] >> 9) << 6) | (uint32_t)lane;
    ull fm = flip_mask(tmm, kmk);
    ull fr = flip_mask(trm, krk);
    float xmv = ((fm >> lane) & 1ull) ? -xpv : xpv;
    float rfv = ((fr >> lane) & 1ull) ? -xpv : xpv;
    // fp16 outputs (identical rounding to former in-kernel cvt)
    float xp_o = __shfl_xor(xpv, 1);
    float xm_o = __shfl_xor(xmv, 1);
    if ((lane & 1) == 0) {
      xp16[n * 32 + (lane >> 1)] = packh2(xpv, xp_o);
      xm16[n * 32 + (lane >> 1)] = packh2(xmv, xm_o);
    }
    ull t64 = __ballot(rfv > 0.0f);
    ull b64v = __ballot(xpv > 0.0f);

    int c1 = yv1[rr] > 0;
    int c2 = yv2[rr] > 0;
    ull p0 = __ballot(c1);
    ull p1 = __ballot(c2);
    int cnt0 = __popcll(p0);
    float cnt = (float)(cnt0 + __popcll(p1));

    unsigned char* pl = poslist + (size_t)n * 64;
    ull below = (lane == 0) ? 0ull : (~0ull >> (64 - lane));
    if (c1) pl[__popcll(p0 & below)] = (unsigned char)lane;
    if (c2) pl[cnt0 + __popcll(p1 & below)] = (unsigned char)(64 + lane);

    if (lane == 0) {
      targ[n] = t64;
      xb[n] = b64v;
      winv[n] = 1.0f / cnt;
      nposA[n] = cnt0 + __popcll(p1);
    }
  }
}

// ---------------- fused MLP + loss epilogue + hamming fold ----
// grid (512, 8, 2); block 512 (8 waves). z0 = map, z1 = net.
// Hamming+cnt is FOLDED into pass-0 m==0 blocks (8 rows/wave, batch-issued
// loads) -- removes the former 4096-block z=2 plane (1/3 of the grid for ~1%
// of the work, each allocating 40KB LDS for a popcount).
// ALL LDS accesses <= 64-bit: measured R1-R5 ladder shows wave64 b128 LDS ops
// serialize ~4x on this access shape regardless of add/XOR swizzle (conflicts
// 4.4M b64-only -> 15.3M +b128-writes -> 59.3M +b128-reads -> 9.0M back at b64).
// Swapped mfma operands: acc reg-dim walks COLUMNS; bias preloaded into acc.
// Pass 0: no logit staging; lse/max from ps/pm partials; picked/hit extracted
// at the owner lane. Pass 1 stages logits via b32 stores for the poslist gather.
__global__ __launch_bounds__(512, 8) void mapnet8(
    const uint32_t* __restrict__ Xm16, const uint32_t* __restrict__ Xp16,
    const _Float16* __restrict__ Wp1, const _Float16* __restrict__ Wp,
    const float* __restrict__ B2s,
    const ull* __restrict__ targ, const float* __restrict__ winv,
    const unsigned char* __restrict__ poslist, const int* __restrict__ nposA,
    const ull* __restrict__ cb64, const ull* __restrict__ xb,
    float* __restrict__ accbuf) {
  __shared__ union {
    _Float16 h[64 * HSS];      // fp16 h-plane, 33280 B
    float lg[32 * LGS];        // logit staging, 33280 B (exact alias)
  } u;
  __shared__ float ps[64 * PSS];   // per-row exp2-sum partials [row][wv]
  __shared__ float pm[64 * PSS];   // per-row max partials (pass 0)
  __shared__ float mvA[64];        // combined per-row max (pass 0)
  __shared__ int   tA[64];         // per-row target byte (pass 0)
  __shared__ float sl[6];          // block accumulators (loss0, loss1, hit, ham, npos)
  const int tid = threadIdx.x, lane = tid & 63, wv = tid >> 6;
  const int q = lane >> 4, lr = lane & 15;
  const int m = blockIdx.y, pass = blockIdx.z;
  const int n0 = blockIdx.x * 64;
  if (tid < 6) sl[tid] = 0.0f;

  const uint32_t* Xin = pass ? Xp16 : Xm16;
  const bool doHam = (pass == 0) && (m == 0);

  // ---- hamming fold (pass0/m0 only): 8 rows per wave, loads batch-issued ----
  float hamS = 0.0f, npS = 0.0f;
  if (doHam) {
    ull xv[8];
    int np[8];
    unsigned char pc[8];
    const int nh = n0 + wv * 8;
#pragma unroll
    for (int r = 0; r < 8; r++) {
      xv[r] = xb[nh + r];
      np[r] = nposA[nh + r];
      pc[r] = poslist[(size_t)(nh + r) * 64 + lane];
    }
#pragma unroll
    for (int r = 0; r < 8; r++) {
      if (lane < np[r]) {
        ull cb = cb64[pc[r]];
        hamS += (float)__popcll(xv[r]) + (float)__popcll(cb) - 2.0f * (float)__popcll(xv[r] & cb);
      }
      npS += (float)np[r];   // uniform per row; only lane 0's copy is used
    }
#pragma unroll
    for (int off = 1; off < 64; off <<= 1) hamS += __shfl_xor(hamS, off);
  }

  // ---- L1 (transposed): wave wv covers rowblock rb = wv&3, t-range (wv>>2)*8..+7
  // W1/B1 pre-scaled by log2e; bias rides K-slot 8 (af[0]=1 on q==1 lanes).
  const int rb = wv & 3, tbase = (wv >> 2) * 8;
  h8 af;
  {
    const _Float16* xsrc = (const _Float16*)(Xin + (size_t)(n0 + rb * 16 + lr) * 32) + m * 8;
    h8 xv = *(const h8*)xsrc;
    h8 zero = {(_Float16)0.0f, (_Float16)0.0f, (_Float16)0.0f, (_Float16)0.0f,
               (_Float16)0.0f, (_Float16)0.0f, (_Float16)0.0f, (_Float16)0.0f};
    af = (q == 0) ? xv : zero;
    if (q == 1) af[0] = (_Float16)1.0f;
  }
#pragma unroll 4
  for (int tt = 0; tt < 8; tt++) {
    int t = tbase + tt;
    h8 wfrag = *(const h8*)(Wp1 + ((size_t)(m * 16 + t) * 64 + lane) * 8);
    f4 z = __builtin_amdgcn_mfma_f32_16x16x32_f16(wfrag, af, (f4){0.f, 0.f, 0.f, 0.f}, 0, 0, 0);
    h4 pk;
#pragma unroll
    for (int reg = 0; reg < 4; reg++) {
      float z2 = z[reg];  // (z+b1)*log2e
      // silu*log2e = z2 * rcp(1 + exp2(-z2)); neg is a free input modifier
      pk[reg] = (_Float16)(z2 * __builtin_amdgcn_rcpf(1.0f + __builtin_amdgcn_exp2f(-z2)));
    }
    *(h4*)(u.h + (size_t)(rb * 16 + lr) * HSS + t * 16 + q * 4) = pk;
  }
  __syncthreads();

  // ---- K loop (swapped operands): acc4[rt][nt][reg] =
  //      logit2[n = rt*16+lr][col = wv*32 + nt*16 + q*4 + reg], bias pre-loaded ----
  f4 acc4[4][2];
  {
    f4 bv0 = *(const f4*)(B2s + m * 256 + wv * 32 + q * 4);
    f4 bv1 = *(const f4*)(B2s + m * 256 + wv * 32 + 16 + q * 4);
#pragma unroll
    for (int rt = 0; rt < 4; rt++) { acc4[rt][0] = bv0; acc4[rt][1] = bv1; }
  }
  const size_t wbase = (size_t)m * 65536;
#pragma unroll 2
  for (int kt = 0; kt < 8; kt++) {
    h8 bh0 = *(const h8*)(Wp + wbase + (((size_t)kt * 16 + wv * 2 + 0) * 64 + lane) * 8);
    h8 bh1 = *(const h8*)(Wp + wbase + (((size_t)kt * 16 + wv * 2 + 1) * 64 + lane) * 8);
#pragma unroll
    for (int rt = 0; rt < 4; rt++) {
      // two b64 LDS reads + merge (measured low-conflict; b128 serializes ~4x)
      const _Float16* p = u.h + (size_t)(rt * 16 + lr) * HSS + kt * 32 + q * 8;
      h4 lo = *(const h4*)p;
      h4 hi = *(const h4*)(p + 4);
      h8 ah = __builtin_shufflevector(lo, hi, 0, 1, 2, 3, 4, 5, 6, 7);
      acc4[rt][0] = __builtin_amdgcn_mfma_f32_16x16x32_f16(bh0, ah, acc4[rt][0], 0, 0, 0);
      acc4[rt][1] = __builtin_amdgcn_mfma_f32_16x16x32_f16(bh1, ah, acc4[rt][1], 0, 0, 0);
    }
  }

  // ---- in-register softmax partials: row rt*16+lr, this wave's 32 cols ----
  float rsum[4], rmax[4];
#pragma unroll
  for (int rt = 0; rt < 4; rt++) {
    f4 l0 = acc4[rt][0], l1 = acc4[rt][1];
    float s = 0.0f;
#pragma unroll
    for (int reg = 0; reg < 4; reg++)
      s += __builtin_amdgcn_exp2f(l0[reg]) + __builtin_amdgcn_exp2f(l1[reg]);
    rsum[rt] = s;
    if (pass == 0) {
      float mv = fmaxf(l0[0], l1[0]);
#pragma unroll
      for (int reg = 1; reg < 4; reg++) mv = fmaxf(mv, fmaxf(l0[reg], l1[reg]));
      rmax[rt] = mv;
    }
  }
#pragma unroll
  for (int rt = 0; rt < 4; rt++) {
    rsum[rt] += __shfl_xor(rsum[rt], 16);
    rsum[rt] += __shfl_xor(rsum[rt], 32);
  }
  if (pass == 0) {
#pragma unroll
    for (int rt = 0; rt < 4; rt++) {
      rmax[rt] = fmaxf(rmax[rt], __shfl_xor(rmax[rt], 16));
      rmax[rt] = fmaxf(rmax[rt], __shfl_xor(rmax[rt], 32));
    }
  }
  if (lane < 16) {
#pragma unroll
    for (int rt = 0; rt < 4; rt++) {
      ps[(rt * 16 + lane) * PSS + wv] = rsum[rt];
      if (pass == 0) pm[(rt * 16 + lane) * PSS + wv] = rmax[rt];
    }
  }

  if (pass == 0) {
    // ---- owner-lane extraction: no logit staging ----
    __syncthreads();
    float myLse = 0.0f;
    if (tid < 64) {
      int row = tid, n = n0 + row;
      f4 s0 = *(const f4*)(ps + row * PSS);
      f4 s1 = *(const f4*)(ps + row * PSS + 4);
      f4 ss = s0 + s1;
      float s = (ss[0] + ss[1]) + (ss[2] + ss[3]);
      f4 m0 = *(const f4*)(pm + row * PSS);
      f4 m1 = *(const f4*)(pm + row * PSS + 4);
      float mv = fmaxf(fmaxf(fmaxf(m0[0], m0[1]), fmaxf(m0[2], m0[3])),
                       fmaxf(fmaxf(m1[0], m1[1]), fmaxf(m1[2], m1[3])));
      mvA[row] = mv;
      tA[row] = (int)((targ[n] >> (m * 8)) & 0xFFull);
      myLse = __builtin_amdgcn_logf(s);   // base-2 lse (bias already in logits)
    }
    __syncthreads();
    float pick = 0.0f, hit = 0.0f;
    const int cbase = wv * 32 + q * 4;
#pragma unroll
    for (int rt = 0; rt < 4; rt++) {
      int row = rt * 16 + lr;
      int d0 = tA[row] - cbase;           // LDS broadcast read
#pragma unroll
      for (int nt = 0; nt < 2; nt++) {
        int d = d0 - nt * 16;
        if ((unsigned)d < 4u) {
          f4 f = acc4[rt][nt];
          float v = f[0];
          v = (d == 1) ? f[1] : v;
          v = (d == 2) ? f[2] : v;
          v = (d == 3) ? f[3] : v;
          pick += v;
          hit += (v == mvA[row]) ? 1.0f : 0.0f;
        }
      }
    }
    float lossC = myLse - pick;
#pragma unroll
    for (int off = 1; off < 64; off <<= 1) {
      lossC += __shfl_xor(lossC, off);
      hit += __shfl_xor(hit, off);
    }
    if (lane == 0) {
      atomicAdd(&sl[0], lossC);
      atomicAdd(&sl[2], hit);
      if (doHam) {
        atomicAdd(&sl[3], hamS);
        atomicAdd(&sl[4], npS);
      }
    }
  } else {
    // ---- pass 1: stage logits (b32 stores) for the poslist gather; two 32-row phases ----
    float partLoss = 0.0f;
    for (int ph = 0; ph < 2; ph++) {
      __syncthreads();
#pragma unroll
      for (int rt2 = 0; rt2 < 2; rt2++) {
#pragma unroll
        for (int nt = 0; nt < 2; nt++)
#pragma unroll
          for (int reg = 0; reg < 4; reg++)
            u.lg[(rt2 * 16 + lr) * LGS + wv * 32 + nt * 16 + q * 4 + reg] =
                acc4[ph * 2 + rt2][nt][reg];
      }
      __syncthreads();
      int rl = tid >> 4;                   // local row 0..31
      int grow = ph * 32 + rl;             // row within block
      int n = n0 + grow;
      int cl = tid & 15;
      const float* lrow = u.lg + rl * LGS;
      int np = nposA[n];
      const unsigned char* pl = poslist + (size_t)n * 64;
      float sp = 0.0f;
      for (int j2 = cl; j2 < np; j2 += 16) {
        int c = pl[j2];
        int t = (int)((cb64[c] >> (m * 8)) & 0xFFull);
        sp += lrow[t];
      }
#pragma unroll
      for (int off = 1; off < 16; off <<= 1) sp += __shfl_xor(sp, off);
      if (cl == 0) {
        f4 s0 = *(const f4*)(ps + grow * PSS);
        f4 s1 = *(const f4*)(ps + grow * PSS + 4);
        f4 ss = s0 + s1;
        float s = (ss[0] + ss[1]) + (ss[2] + ss[3]);
        partLoss += __builtin_amdgcn_logf(s) - winv[n] * sp;
      }
    }
    partLoss += __shfl_xor(partLoss, 16);
    partLoss += __shfl_xor(partLoss, 32);
    if (lane == 0) atomicAdd(&sl[1], partLoss);
  }

  __syncthreads();
  if (tid == 0) {
    float* slot = accbuf + (blockIdx.x & 127) * 8;
    if (pass == 0) {
      atomicAdd(&slot[0], sl[0]);
      atomicAdd(&slot[2], sl[2]);
      if (doHam) {
        atomicAdd(&slot[3], sl[3]);
        atomicAdd(&slot[4], sl[4]);
      }
    } else {
      atomicAdd(&slot[1], sl[1]);
    }
  }
}

__global__ __launch_bounds__(128) void finalk(const float* __restrict__ accbuf, float* __restrict__ out) {
  int t = threadIdx.x;  // 0..127
  float v0 = accbuf[t * 8 + 0], v1 = accbuf[t * 8 + 1], v2 = accbuf[t * 8 + 2];
  float v3 = accbuf[t * 8 + 3], v4 = accbuf[t * 8 + 4];
#pragma unroll
  for (int off = 1; off < 64; off <<= 1) {
    v0 += __shfl_xor(v0, off); v1 += __shfl_xor(v1, off); v2 += __shfl_xor(v2, off);
    v3 += __shfl_xor(v3, off); v4 += __shfl_xor(v4, off);
  }
  __shared__ float s[2][5];
  if ((t & 63) == 0) {
    s[t >> 6][0] = v0; s[t >> 6][1] = v1; s[t >> 6][2] = v2; s[t >> 6][3] = v3; s[t >> 6][4] = v4;
  }
  __syncthreads();
  if (t == 0) {
    float a0 = s[0][0] + s[1][0], a1 = s[0][1] + s[1][1], a2 = s[0][2] + s[1][2];
    float a3 = s[0][3] + s[1][3], a4 = s[0][4] + s[1][4];
    // losses accumulated in base-2 (exp2-domain logits): scale back by ln2 here.
    float netLoss = a1 * LN2F / (float)NR;
    float mapLoss = a0 * LN2F / (float)NR;
    out[0] = netLoss + mapLoss;
    out[1] = netLoss;
    out[2] = mapLoss;
    out[3] = a2 / (float)(NR * MM);
    out[4] = a3 / a4;
  }
}

extern "C" void kernel_launch(void* const* d_in, const int* in_sizes, int n_in,
                              void* d_out, int out_size, void* d_ws, size_t ws_size,
                              hipStream_t stream) {
  const float* x = (const float*)d_in[0];
  const int* y = (const int*)d_in[1];
  const float* centroids = (const float*)d_in[2];
  const int* perm = (const int*)d_in[3];
  const void* tmap = d_in[4];
  const void* traw = d_in[5];
  const float* W1 = (const float*)d_in[6];
  const float* B1 = (const float*)d_in[7];
  const float* W2 = (const float*)d_in[8];
  const float* B2 = (const float*)d_in[9];
  float* out = (float*)d_out;

  char* w = (char*)d_ws;
  float* accbuf = (float*)w;                                  // 128 slots x 8 floats = 4 KB
  uint32_t* xp16 = (uint32_t*)(w + 4096);                     // 4 MB (fp16 pairs)
  uint32_t* xm16 = xp16 + (size_t)NR * 32;                    // 4 MB
  ull* targ = (ull*)(xm16 + (size_t)NR * 32);                 // 256 KB
  ull* cb64 = targ + NR;                                      // 1 KB (128 slots)
  ull* xb = cb64 + 128;                                       // 256 KB
  float* winv = (float*)(xb + NR);                            // 128 KB
  int* nposA = (int*)(winv + NR);                             // 128 KB
  unsigned char* poslist = (unsigned char*)(nposA + NR);      // 2 MB
  _Float16* Wp = (_Float16*)(poslist + (size_t)NR * 64);      // 1 MB (fp16 frags)
  _Float16* Wp1 = Wp + (1 << 19);                             // 128 KB (L1 frags)
  float* B2s = (float*)(Wp1 + (1 << 16));                     // 8 KB (B2 * log2e)

  hipMemsetAsync(accbuf, 0, 4096, stream);

  // jax.random.key(1) -> (0,1); split -> kmap=(w0(0,2), w0(1,3)), kraw=(w1(0,2), w1(1,3))
  uint32_t a0, b0, a1, b1;
  tf2x32(0u, 1u, 0u, 2u, a0, b0);
  tf2x32(0u, 1u, 1u, 3u, a1, b1);

  stage1p<<<2048 + 314, 256, 0, stream>>>(x, y, perm, tmap, traw, a0, a1, b0, b1,
                                          W2, W1, B1, B2, centroids, Wp, Wp1, B2s, cb64,
                                          xp16, xm16, targ, xb, winv, poslist, nposA);
  dim3 g(NR / 64, MM, 2);
  mapnet8<<<g, 512, 0, stream>>>(xm16, xp16, Wp1, Wp, B2s, targ, winv, poslist, nposA,
                                 cb64, xb, accbuf);
  finalk<<<1, 128, 0, stream>>>(accbuf, out);
}